// Round 7
// baseline (1244.677 us; speedup 1.0000x reference)
//
#include <hip/hip_runtime.h>
#include <cstdint>
#include <cstddef>

// Problem dims
#define BDIM 8192
#define D1 1024
#define HDIM 4096

typedef __attribute__((ext_vector_type(8))) short short8;
typedef __attribute__((ext_vector_type(4))) float f32x4;
typedef __attribute__((ext_vector_type(4))) unsigned short u16x4;

__device__ inline void async_load16(const void* g, void* l) {
  __builtin_amdgcn_global_load_lds(
      (const __attribute__((address_space(1))) void*)g,
      (__attribute__((address_space(3))) void*)l,
      16 /*bytes*/, 0 /*offset*/, 0 /*aux*/);
}

__device__ inline unsigned short f2bf(float f) {
  union { float f; uint32_t u; } v; v.f = f;
  uint32_t u = v.u;
  uint32_t r = u + 0x7FFFu + ((u >> 16) & 1u);  // RNE
  return (unsigned short)(r >> 16);
}
__device__ inline float bf2f(unsigned short u) {
  union { uint32_t u; float f; } v; v.u = (uint32_t)u << 16; return v.f;
}

// ---------------------------------------------------------------------------
// 256x256 tile, 4 waves (1/SIMD), wave-tile 128x128, BK=32, 4 LDS buffers.
// C = act(A @ B^T + bias), bf16 in/out. gridDim.z=2 selects (A,B,bias,C).
//
// Rationale (r5 post-mortem): with 8 lockstep waves the MFMA pipe (2483cyc)
// and LDS-read pipe (2304cyc) serialize per tile. Here:
//  - 1 wave/SIMD, acc[8][8] (256 VGPR; 512 budget at 1 wave/EU) halves the
//    fragment re-read factor: LDS reads 64KB/tile vs 96KB (2-wave sharing).
//  - per tile: MFMA burst consumes regs read ONE TILE EARLIER -> zero lgkm
//    wait; the 16 ds_reads for tile t+1 issue before the burst (pinned by
//    sched_barrier(0)) and complete under the MFMA burst.
//  - stage tile t+3 (8 global_load_lds), vmcnt(16) -> exactly tile t+1
//    drains; 1 barrier/tile. vmcnt never 0 in the loop.
// RAW: read of buf b happens after vmcnt(16)+barrier that drained its stage.
// WAR: stage of buf (t+3)&3=(t-1)&3 issues >= one full MFMA burst + barrier
// after all reads of it completed (same separation as r2-r5, refcheck'd).
// LDS: A [4][256][32] @0, B same @32768 ushorts = 128KB.
// Swizzle: 16B slot p of row r holds k-group p ^ ((r>>1)&3) (involution),
// applied on the pre-swizzled global source and the ds_read -> 2-way free.
// (Round 6 bench was an infra failure — "container failed twice", no run;
//  this is the same kernel resubmitted after a fresh hazard audit.)
// ---------------------------------------------------------------------------
__global__ __launch_bounds__(256, 1)
void gemm8(const unsigned short* __restrict__ A0,
           const unsigned short* __restrict__ A1, int lda,
           const unsigned short* __restrict__ B0,
           const unsigned short* __restrict__ B1,
           const float* __restrict__ bias0, const float* __restrict__ bias1,
           unsigned short* __restrict__ C0, unsigned short* __restrict__ C1,
           int ldc, int K, int relu) {
  __shared__ __align__(16) unsigned short smem[65536];  // A:[0,32768) B:[32768,65536)

  const int z = blockIdx.z;
  const unsigned short* A  = z ? A1 : A0;
  const unsigned short* Bw = z ? B1 : B0;
  const float* biasP       = z ? bias1 : bias0;
  unsigned short* C        = z ? C1 : C0;

  // bijective XCD swizzle (m204)
  const int nX  = gridDim.x;
  const int nwg = gridDim.x * gridDim.y;
  const int bid = blockIdx.y * gridDim.x + blockIdx.x;
  const int q = nwg >> 3, r = nwg & 7;
  const int xcd = bid & 7, rest = bid >> 3;
  const int wg = (xcd < r ? xcd * (q + 1) : r * (q + 1) + (xcd - r) * q) + rest;
  const int tm = wg / nX, tn = wg % nX;
  const int m0 = tm * 256, n0 = tn * 256;

  const int tid  = threadIdx.x;
  const int wave = tid >> 6, lane = tid & 63;
  const int quad = lane >> 4, l15 = lane & 15;
  const int wm = wave >> 1, wn = wave & 1;   // 2x2 wave grid; wave tile 128x128

  // staging source (pre-swizzled global address; LDS dest stays linear)
  const int sr    = tid >> 2;                         // 0..63 (+64 per round)
  const int sslot = (tid & 3) ^ ((tid >> 3) & 3);     // involutive 16B-slot swizzle
  const unsigned short* gA = A  + (long)(m0 + sr) * lda + sslot * 8;
  const unsigned short* gB = Bw + (long)(n0 + sr) * K   + sslot * 8;

  // LDS read bases (swizzled): row = w*128 + fr*16 + l15, k-slot quad
  const int swz = ((quad ^ ((l15 >> 1) & 3)) << 3);   // ushort units
  const unsigned short* aRd = smem + wm * 4096 + l15 * 32 + swz;
  const unsigned short* bRd = smem + 32768 + wn * 4096 + l15 * 32 + swz;

  f32x4 acc[8][8] = {};
  const int NT = K >> 5;   // BK=32 tiles

#define STAGE(SB, KT) { \
  const int kt_ = (KT) < NT ? (KT) : NT - 1; \
  const unsigned short* ga_ = gA + (long)kt_ * 32; \
  const unsigned short* gb_ = gB + (long)kt_ * 32; \
  unsigned short* la_ = smem + (SB)*8192 + wave*512; \
  unsigned short* lb_ = smem + 32768 + (SB)*8192 + wave*512; \
  async_load16(ga_,                    la_); \
  async_load16(ga_ +  64*(long)lda,    la_ + 2048); \
  async_load16(ga_ + 128*(long)lda,    la_ + 4096); \
  async_load16(ga_ + 192*(long)lda,    la_ + 6144); \
  async_load16(gb_,                    lb_); \
  async_load16(gb_ +  64*(long)K,      lb_ + 2048); \
  async_load16(gb_ + 128*(long)K,      lb_ + 4096); \
  async_load16(gb_ + 192*(long)K,      lb_ + 6144); }

#define READ8(d, BASE, BUF) { \
  _Pragma("unroll") \
  for (int fr = 0; fr < 8; ++fr) \
    d[fr] = *(const short8*)((BASE) + (BUF)*8192 + fr*512); }

#define MFMA64(CA, CB) \
  _Pragma("unroll") \
  for (int mt = 0; mt < 8; ++mt) { \
    _Pragma("unroll") \
    for (int nt = 0; nt < 8; ++nt) { \
      acc[mt][nt] = __builtin_amdgcn_mfma_f32_16x16x32_bf16( \
          CA[mt], CB[nt], acc[mt][nt], 0, 0, 0); \
    } }

#define BARRIER() asm volatile("s_barrier" ::: "memory")
#define VMCNT16() asm volatile("s_waitcnt vmcnt(16)" ::: "memory")

// Tile t: buf=BUF holds t (cur in CA/CB); stage t+3 -> SB; read t+1 from NXB.
#define STEP(BUF, NXB, SB, CA, CB, NA, NB, KTX) { \
  STAGE(SB, KTX); \
  VMCNT16(); \
  BARRIER(); \
  READ8(NA, aRd, NXB); READ8(NB, bRd, NXB); \
  __builtin_amdgcn_sched_barrier(0); \
  MFMA64(CA, CB); \
}

  short8 pa[8], pb[8], qa[8], qb[8];

  // prologue: stage tiles 0,1,2 into bufs 0,1,2 (24 loads outstanding)
  STAGE(0, 0); STAGE(1, 1); STAGE(2, 2);
  VMCNT16();       // drain tile 0's 8 loads; tiles 1,2 stay in flight
  BARRIER();
  READ8(pa, aRd, 0); READ8(pb, bRd, 0);   // cur = tile 0

#pragma unroll 1
  for (int t = 0; t < NT; t += 4) {
    STEP(0, 1, 3, pa, pb, qa, qb, t + 3);
    STEP(1, 2, 0, qa, qb, pa, pb, t + 4);
    STEP(2, 3, 1, pa, pb, qa, qb, t + 5);
    STEP(3, 0, 2, qa, qb, pa, pb, t + 6);
  }

  // ---- epilogue: drain stage loads, then LDS-bounce for coalesced C writes --
  asm volatile("s_waitcnt vmcnt(0)" ::: "memory");
  BARRIER();   // all waves past MFMA (lgkm-complete) and all loads landed

  unsigned short* sc = smem + wave * 16384;  // private 128x128 bf16 scratch/wave
#pragma unroll
  for (int nt = 0; nt < 8; ++nt) {
    const int col = n0 + wn * 128 + nt * 16 + l15;
    const float bv = biasP[col];
#pragma unroll
    for (int mt = 0; mt < 8; ++mt) {
#pragma unroll
      for (int rr = 0; rr < 4; ++rr) {
        const int lrow = mt * 16 + quad * 4 + rr;
        float v = acc[mt][nt][rr] + bv;
        if (relu) v = v > 0.f ? v : 0.f;
        // scratch XOR: col bits 4-6 ^= row bits 2-4 (bank spread)
        sc[lrow * 128 + ((nt * 16 + l15) ^ (((lrow >> 2) & 7) << 4))] = f2bf(v);
      }
    }
  }
  // per-wave private region: no barrier needed (wave-ordered DS ops)
  const long rowbase = m0 + wm * 128;
  const int colbase  = n0 + wn * 128;
#pragma unroll
  for (int i = 0; i < 32; ++i) {
    const int L   = i * 1024 + lane * 16;   // byte offset in wave scratch
    const int row = L >> 8;                 // 256B per row
    const int sp  = (L & 255) >> 4;         // 16B slot in row
    const int cg  = sp ^ (((row >> 2) & 7) << 1);   // undo col-bit XOR (slot bits 1-3)
    short8 v = *(const short8*)&sc[row * 128 + sp * 8];
    *(short8*)&C[(rowbase + row) * (long)ldc + colbase + cg * 8] = v;
  }

#undef STAGE
#undef READ8
#undef MFMA64
#undef BARRIER
#undef VMCNT16
#undef STEP
}

// ---------------------------------------------------------------------------
// Coupling epilogue: sv=tanh(s); y = x[:,xoff+c]*exp(sv)+t; optional y->bf16;
// ld[row] = (or +=) rowsum(sv). One block per row, no atomics.
// NOTE: sb and y1b may alias (in-place); no __restrict__ on them.
// ---------------------------------------------------------------------------
__global__ __launch_bounds__(256)
void couple(const unsigned short* sb, const unsigned short* __restrict__ tb,
            const float* __restrict__ x, float* __restrict__ y,
            unsigned short* y1b, float* __restrict__ ld,
            long growoff, int xoff, int addld) {
  __shared__ float wsum[4];
  const int row = blockIdx.x;
  const long grow = growoff + row;
  const int c = threadIdx.x * 4;

  u16x4 sv4 = *(const u16x4*)&sb[(long)row * 1024 + c];
  u16x4 tv4 = *(const u16x4*)&tb[(long)row * 1024 + c];
  f32x4 xv  = *(const f32x4*)&x[grow * 2048 + xoff + c];
  f32x4 yv;
  unsigned short yb[4];
  float rs = 0.f;
#pragma unroll
  for (int j = 0; j < 4; ++j) {
    float s  = bf2f(sv4[j]);
    float t  = bf2f(tv4[j]);
    float sv = tanhf(s);           // SCALE_LIMIT = 1.0
    rs += sv;
    float yy = xv[j] * __expf(sv) + t;
    yv[j] = yy;
    yb[j] = f2bf(yy);
  }
  *(f32x4*)&y[grow * 2048 + xoff + c] = yv;
  if (y1b) {
    u16x4 o; o[0] = yb[0]; o[1] = yb[1]; o[2] = yb[2]; o[3] = yb[3];
    *(u16x4*)&y1b[(long)row * 1024 + c] = o;
  }
#pragma unroll
  for (int o = 32; o > 0; o >>= 1) rs += __shfl_down(rs, o);
  const int wv = threadIdx.x >> 6, ln = threadIdx.x & 63;
  if (ln == 0) wsum[wv] = rs;
  __syncthreads();
  if (threadIdx.x == 0) {
    float tot = wsum[0] + wsum[1] + wsum[2] + wsum[3];
    if (addld) ld[grow] += tot; else ld[grow] = tot;
  }
}

// ---------------------------------------------------------------------------
// Batched transpose + fp32->bf16 cast: in[R,C] fp32 -> out[C,R] bf16.
// gridDim.z (<=4) selects the (src,dst) pair.
// ---------------------------------------------------------------------------
__global__ __launch_bounds__(256)
void transpose_cast4(const float* __restrict__ s0, const float* __restrict__ s1,
                     const float* __restrict__ s2, const float* __restrict__ s3,
                     unsigned short* __restrict__ d0, unsigned short* __restrict__ d1,
                     unsigned short* __restrict__ d2, unsigned short* __restrict__ d3,
                     int R, int C) {
  __shared__ float tile[32][33];
  const int bz = blockIdx.z;
  const float* in = bz == 0 ? s0 : bz == 1 ? s1 : bz == 2 ? s2 : s3;
  unsigned short* out = bz == 0 ? d0 : bz == 1 ? d1 : bz == 2 ? d2 : d3;
  const int bx = blockIdx.x * 32;
  const int by = blockIdx.y * 32;
  const int tx = threadIdx.x & 31;
  const int ty = threadIdx.x >> 5;
  for (int j = ty; j < 32; j += 8)
    tile[j][tx] = in[(long)(by + j) * C + bx + tx];
  __syncthreads();
  for (int j = ty; j < 32; j += 8)
    out[(long)(bx + j) * R + by + tx] = f2bf(tile[tx][j]);
}

// x (B, 2048) fp32 -> x2 bf16 packed (B, 1024)
__global__ __launch_bounds__(256)
void cast_x2(const float* __restrict__ x, unsigned short* __restrict__ x2b) {
  long i = (long)blockIdx.x * 256 + threadIdx.x;
  long row = i >> 10, col = i & 1023;
  x2b[i] = f2bf(x[row * (2 * D1) + D1 + col]);
}

// ---------------------------------------------------------------------------
extern "C" void kernel_launch(void* const* d_in, const int* in_sizes, int n_in,
                              void* d_out, int out_size, void* d_ws, size_t ws_size,
                              hipStream_t stream) {
  const float* x     = (const float*)d_in[0];
  const float* s1_W1 = (const float*)d_in[1];
  const float* s1_b1 = (const float*)d_in[2];
  const float* s1_W2 = (const float*)d_in[3];
  const float* s1_b2 = (const float*)d_in[4];
  const float* t1_W1 = (const float*)d_in[5];
  const float* t1_b1 = (const float*)d_in[6];
  const float* t1_W2 = (const float*)d_in[7];
  const float* t1_b2 = (const float*)d_in[8];
  const float* s2_W1 = (const float*)d_in[9];
  const float* s2_b1 = (const float*)d_in[10];
  const float* s2_W2 = (const float*)d_in[11];
  const float* s2_b2 = (const float*)d_in[12];
  const float* t2_W1 = (const float*)d_in[13];
  const float* t2_b1 = (const float*)d_in[14];
  const float* t2_W2 = (const float*)d_in[15];
  const float* t2_b2 = (const float*)d_in[16];

  const size_t MB = 1024UL * 1024UL;
  float* y_out  = (float*)d_out;                           // (B, 2048)
  float* ld_out = (float*)d_out + (long)BDIM * (2 * D1);   // (B,)
  char* ws = (char*)d_ws;

  if (ws_size >= 192 * MB) {
    // 192MB layout: w1a@0 w1b@8 w2a@16 w2b@24 | x2b/sbuf@32 (16MB)
    //               tbuf@48 (16MB) | h@64 (128MB). Mid-stream re-transposes.
    unsigned short* w1a = (unsigned short*)(ws + 0 * MB);
    unsigned short* w1b = (unsigned short*)(ws + 8 * MB);
    unsigned short* w2a = (unsigned short*)(ws + 16 * MB);
    unsigned short* w2b = (unsigned short*)(ws + 24 * MB);
    unsigned short* x2b = (unsigned short*)(ws + 32 * MB);  // x2 -> s -> y1 -> s
    unsigned short* tb  = (unsigned short*)(ws + 48 * MB);
    unsigned short* h   = (unsigned short*)(ws + 64 * MB);

    cast_x2<<<(BDIM * D1) / 256, 256, 0, stream>>>(x, x2b);
    transpose_cast4<<<dim3(HDIM / 32, D1 / 32, 2), 256, 0, stream>>>(
        s1_W1, t1_W1, s1_W1, s1_W1, w1a, w1b, w1a, w1a, D1, HDIM);
    transpose_cast4<<<dim3(D1 / 32, HDIM / 32, 2), 256, 0, stream>>>(
        s1_W2, t1_W2, s1_W2, s1_W2, w2a, w2b, w2a, w2a, HDIM, D1);

    // ---- stage 1 ----
    gemm8<<<dim3(16, 32, 2), 256, 0, stream>>>(x2b, x2b, D1, w1a, w1b,
        s1_b1, t1_b1, h, h + 4096, 2 * HDIM, D1, 1);
    transpose_cast4<<<dim3(HDIM / 32, D1 / 32, 2), 256, 0, stream>>>(
        s2_W1, t2_W1, s2_W1, s2_W1, w1a, w1b, w1a, w1a, D1, HDIM);
    gemm8<<<dim3(4, 32, 2), 256, 0, stream>>>(h, h + 4096, 2 * HDIM, w2a, w2b,
        s1_b2, t1_b2, x2b /*sbuf*/, tb, D1, HDIM, 0);
    transpose_cast4<<<dim3(D1 / 32, HDIM / 32, 2), 256, 0, stream>>>(
        s2_W2, t2_W2, s2_W2, s2_W2, w2a, w2b, w2a, w2a, HDIM, D1);
    couple<<<BDIM, 256, 0, stream>>>(x2b, tb, x, y_out, x2b /*y1b in place*/,
                                     ld_out, 0, 0, 0);
    // ---- stage 2 ----
    gemm8<<<dim3(16, 32, 2), 256, 0, stream>>>(x2b, x2b, D1, w1a, w1b,
        s2_b1, t2_b1, h, h + 4096, 2 * HDIM, D1, 1);
    gemm8<<<dim3(4, 32, 2), 256, 0, stream>>>(h, h + 4096, 2 * HDIM, w2a, w2b,
        s2_b2, t2_b2, x2b /*sbuf*/, tb, D1, HDIM, 0);
    couple<<<BDIM, 256, 0, stream>>>(x2b, tb, x, y_out, nullptr, ld_out, 0, D1, 1);
  } else {
    // Chunked fallback: all 8 weight buffers persistent (64MB) + x2b (16MB)
    // + per-chunk tbuf (16/NC) + h (128/NC).
    int NC = 2;
    while (NC < 16) {
      size_t need = 80 * MB + (16 * MB) / NC + (128 * MB) / NC;
      if (need <= ws_size) break;
      NC <<= 1;
    }
    const int Mrows = BDIM / NC;
    unsigned short* w1s1 = (unsigned short*)(ws + 0 * MB);
    unsigned short* w1t1 = (unsigned short*)(ws + 8 * MB);
    unsigned short* w1s2 = (unsigned short*)(ws + 16 * MB);
    unsigned short* w1t2 = (unsigned short*)(ws + 24 * MB);
    unsigned short* w2s1 = (unsigned short*)(ws + 32 * MB);
    unsigned short* w2t1 = (unsigned short*)(ws + 40 * MB);
    unsigned short* w2s2 = (unsigned short*)(ws + 48 * MB);
    unsigned short* w2t2 = (unsigned short*)(ws + 56 * MB);
    unsigned short* x2b  = (unsigned short*)(ws + 64 * MB);
    unsigned short* tb   = (unsigned short*)(ws + 80 * MB);
    unsigned short* h    = (unsigned short*)(ws + 80 * MB + (16 * MB) / NC);

    cast_x2<<<(BDIM * D1) / 256, 256, 0, stream>>>(x, x2b);
    transpose_cast4<<<dim3(HDIM / 32, D1 / 32, 4), 256, 0, stream>>>(
        s1_W1, t1_W1, s2_W1, t2_W1, w1s1, w1t1, w1s2, w1t2, D1, HDIM);
    transpose_cast4<<<dim3(D1 / 32, HDIM / 32, 4), 256, 0, stream>>>(
        s1_W2, t1_W2, s2_W2, t2_W2, w2s1, w2t1, w2s2, w2t2, HDIM, D1);

    for (int c = 0; c < NC; ++c) {
      const long moff = (long)c * Mrows;
      unsigned short* xA = x2b + moff * D1;
      gemm8<<<dim3(16, Mrows / 256, 2), 256, 0, stream>>>(xA, xA, D1, w1s1, w1t1,
          s1_b1, t1_b1, h, h + 4096, 2 * HDIM, D1, 1);
      gemm8<<<dim3(4, Mrows / 256, 2), 256, 0, stream>>>(h, h + 4096, 2 * HDIM,
          w2s1, w2t1, s1_b2, t1_b2, xA, tb, D1, HDIM, 0);
      couple<<<Mrows, 256, 0, stream>>>(xA, tb, x, y_out, xA, ld_out, moff, 0, 0);
      gemm8<<<dim3(16, Mrows / 256, 2), 256, 0, stream>>>(xA, xA, D1, w1s2, w1t2,
          s2_b1, t2_b1, h, h + 4096, 2 * HDIM, D1, 1);
      gemm8<<<dim3(4, Mrows / 256, 2), 256, 0, stream>>>(h, h + 4096, 2 * HDIM,
          w2s2, w2t2, s2_b2, t2_b2, xA, tb, D1, HDIM, 0);
      couple<<<Mrows, 256, 0, stream>>>(xA, tb, x, y_out, nullptr, ld_out, moff, D1, 1);
    }
  }
}